// Round 11
// baseline (129.395 us; speedup 1.0000x reference)
//
#include <hip/hip_runtime.h>

// HyperLayer: y[b, f0/c0] += v * w0 * (wf1*x[b,f1] + wc1*x[b,c1])
// B=16, N=262144, DIM=8192.
// R11: R1-R10 invariant: ~50us whenever scattered lane-word-accesses/point
// == 4 (any LDS/VMEM mix, any occupancy, any load schedule). Model:
// scattered addresses consume ~2 lanes/cyc/CU (AGU rate). Test: cut 4->3 by
// pre-pairing x into float2 (x_pair[i] = {x[i], x[i+1]}, 1MB in ws) so the
// gather is ONE scattered b64 instead of two b32. Predict ~37-40us scatter.

#define BATCH 16
#define NPTS 262144
#define DIM 8192
#define SPLITS 32
#define PTS_PER_BLOCK (NPTS / SPLITS)   // 8192
#define BLOCK 512

// Build x_pair[b][i] = (x[b][i], x[b][i+1]); last element pairs with 0.
__global__ __launch_bounds__(256) void make_pairs_kernel(
    const float* __restrict__ x, float2* __restrict__ x_pair)
{
    const int g = blockIdx.x * 256 + threadIdx.x;   // [0, B*DIM)
    const int b = g / DIM, i = g % DIM;
    const float* row = x + (size_t)b * DIM;
    float a = row[i];
    float c = (i + 1 < DIM) ? row[i + 1] : 0.0f;
    x_pair[g] = make_float2(a, c);
}

__global__ __launch_bounds__(BLOCK, 4) void hyper_scatter_kernel(
    const float2* __restrict__ x_pair,  // [B, DIM] pairs (L1-resident row)
    const float* __restrict__ ri,       // [B, N, 2]
    const float* __restrict__ rv,       // [B, N]
    float* __restrict__ partials)       // [B*SPLITS, DIM]
{
    __shared__ float y_s[DIM];   // 32 KB accumulator

    const int tid   = threadIdx.x;
    const int split = blockIdx.x;
    const int b     = blockIdx.y;

    float4* ys4 = (float4*)y_s;
    #pragma unroll
    for (int i = tid; i < DIM / 4; i += BLOCK) {
        ys4[i] = make_float4(0.f, 0.f, 0.f, 0.f);
    }
    __syncthreads();

    const float2* xprow = x_pair + (size_t)b * DIM;
    const size_t base = (size_t)b * NPTS + (size_t)split * PTS_PER_BLOCK;
    const float2* idx2 = (const float2*)ri + base;
    const float*  val  = rv + base;

    #pragma unroll 4
    for (int i = tid; i < PTS_PER_BLOCK; i += BLOCK) {
        float2 r = idx2[i];
        float v  = val[i];

        float f0 = floorf(r.x), c0 = ceilf(r.x);
        float f1 = floorf(r.y), c1 = ceilf(r.y);
        // Per reference: w = 1 - |corner - real|, floor/ceil independently
        // (both corners get weight 1 when floor==ceil -> double count).
        float wf0 = 1.0f - (r.x - f0), wc0 = 1.0f - (c0 - r.x);
        float wf1 = 1.0f - (r.y - f1), wc1 = 1.0f - (c1 - r.y);

        // ONE scattered b64 gather: (x[f1], x[f1+1]).
        float2 g = xprow[(int)f1];
        float xa = g.x;
        float xb = (c1 == f1) ? xa : g.y;   // integral r.y: both corners = x[f1]

        float vg = v * (wf1 * xa + wc1 * xb);
        unsafeAtomicAdd(&y_s[(int)f0], wf0 * vg);   // native ds_add_f32
        unsafeAtomicAdd(&y_s[(int)c0], wc0 * vg);
    }
    __syncthreads();

    // Coalesced float4 store of the partial row (no atomics).
    float4* out4 = (float4*)(partials + ((size_t)b * SPLITS + split) * DIM);
    #pragma unroll
    for (int i = tid; i < DIM / 4; i += BLOCK) {
        out4[i] = ys4[i];
    }
}

// y[b][d] = sum_s partials[b*SPLITS+s][d]; one float4 per thread.
__global__ __launch_bounds__(256) void reduce_partials_kernel(
    const float* __restrict__ partials, float* __restrict__ y)
{
    const int d4 = blockIdx.x * 256 + threadIdx.x;      // [0, B*DIM/4)
    const int b   = d4 / (DIM / 4);
    const int off = d4 % (DIM / 4);
    const float4* p = (const float4*)(partials + (size_t)b * SPLITS * DIM) + off;
    float4 acc = make_float4(0.f, 0.f, 0.f, 0.f);
    #pragma unroll
    for (int s = 0; s < SPLITS; ++s) {
        float4 v = p[(size_t)s * (DIM / 4)];
        acc.x += v.x; acc.y += v.y; acc.z += v.z; acc.w += v.w;
    }
    ((float4*)y)[d4] = acc;
}

// Fallback (ws too small): R10-style, two b32 gathers + global-atomic flush.
__global__ __launch_bounds__(BLOCK, 4) void hyper_scatter_atomic_kernel(
    const float* __restrict__ x, const float* __restrict__ ri,
    const float* __restrict__ rv, float* __restrict__ y)
{
    __shared__ float y_s[DIM];
    const int tid = threadIdx.x, split = blockIdx.x, b = blockIdx.y;
    float4* ys4 = (float4*)y_s;
    for (int i = tid; i < DIM / 4; i += BLOCK) {
        ys4[i] = make_float4(0.f, 0.f, 0.f, 0.f);
    }
    __syncthreads();
    const float* xrow = x + (size_t)b * DIM;
    const size_t base = (size_t)b * NPTS + (size_t)split * PTS_PER_BLOCK;
    const float2* idx2 = (const float2*)ri + base;
    const float*  val  = rv + base;
    for (int i = tid; i < PTS_PER_BLOCK; i += BLOCK) {
        float2 r = idx2[i];
        float v  = val[i];
        float f0 = floorf(r.x), c0 = ceilf(r.x);
        float f1 = floorf(r.y), c1 = ceilf(r.y);
        float wf0 = 1.0f - (r.x - f0), wc0 = 1.0f - (c0 - r.x);
        float wf1 = 1.0f - (r.y - f1), wc1 = 1.0f - (c1 - r.y);
        float vg = v * (wf1 * xrow[(int)f1] + wc1 * xrow[(int)c1]);
        unsafeAtomicAdd(&y_s[(int)f0], wf0 * vg);
        unsafeAtomicAdd(&y_s[(int)c0], wc0 * vg);
    }
    __syncthreads();
    float* yrow = y + (size_t)b * DIM;
    for (int i = tid; i < DIM; i += BLOCK) atomicAdd(&yrow[i], y_s[i]);
}

extern "C" void kernel_launch(void* const* d_in, const int* in_sizes, int n_in,
                              void* d_out, int out_size, void* d_ws, size_t ws_size,
                              hipStream_t stream) {
    const float* x  = (const float*)d_in[0];
    const float* ri = (const float*)d_in[1];
    const float* rv = (const float*)d_in[2];
    float* y = (float*)d_out;

    const size_t part_bytes = (size_t)BATCH * SPLITS * DIM * sizeof(float); // 16 MB
    const size_t pair_bytes = (size_t)BATCH * DIM * sizeof(float2);         // 1 MB
    dim3 grid(SPLITS, BATCH);

    if (ws_size >= part_bytes + pair_bytes) {
        float* partials = (float*)d_ws;
        float2* x_pair  = (float2*)((char*)d_ws + part_bytes);
        make_pairs_kernel<<<BATCH * DIM / 256, 256, 0, stream>>>(x, x_pair);
        hyper_scatter_kernel<<<grid, BLOCK, 0, stream>>>(x_pair, ri, rv, partials);
        const int n4 = BATCH * DIM / 4;  // 32768
        reduce_partials_kernel<<<n4 / 256, 256, 0, stream>>>(partials, y);
    } else {
        hipMemsetAsync(y, 0, (size_t)out_size * sizeof(float), stream);
        hyper_scatter_atomic_kernel<<<grid, BLOCK, 0, stream>>>(x, ri, rv, y);
    }
}

// Round 13
// 114.179 us; speedup vs baseline: 1.1333x; 1.1333x over previous
//
#include <hip/hip_runtime.h>

// HyperLayer: y[b, f0/c0] += v * w0 * (wf1*x[b,f1] + wc1*x[b,c1])
// B=16, N=262144, DIM=8192.
// R13: model after R1-R12: scattered ds_add_f32 costs ~230cyc/wave-instr
// (~3.6 cyc/lane, serialized through a narrow LDS FP-add unit), while
// scattered ds_read is near-free (conflict counter ~2.6K cyc/CU). Integer
// LDS atomics are per-bank full-rate on GCN/CDNA lineage. Switch the
// accumulator to fixed-point int32 (scale 2^22): ds_add_u32 instead of
// ds_add_f32. Wraparound-exact two's complement; worst-case per-slot
// per-block |sum|~300*2^22 = 1.26e9 < 2^31; quantization ~2e-5 per output.
// R12's fp16 packing reverted (RTZ bias + fp16 tails -> absmax 2.27).

#define BATCH 16
#define NPTS 262144
#define DIM 8192
#define SPLITS 32
#define PTS_PER_BLOCK (NPTS / SPLITS)   // 8192
#define BLOCK 512

#define FP_SCALE 4194304.0f             // 2^22
#define FP_INV   (1.0f / 4194304.0f)

// Build x_pair[b][i] = (x[b][i], x[b][i+1]); last element pairs with 0.
__global__ __launch_bounds__(256) void make_pairs_kernel(
    const float* __restrict__ x, float2* __restrict__ x_pair)
{
    const int g = blockIdx.x * 256 + threadIdx.x;   // [0, B*DIM)
    const int b = g / DIM, i = g % DIM;
    const float* row = x + (size_t)b * DIM;
    float a = row[i];
    float c = (i + 1 < DIM) ? row[i + 1] : 0.0f;
    x_pair[g] = make_float2(a, c);
}

__global__ __launch_bounds__(BLOCK, 4) void hyper_scatter_kernel(
    const float2* __restrict__ x_pair,  // [B, DIM] pairs (L1-resident row)
    const float* __restrict__ ri,       // [B, N, 2]
    const float* __restrict__ rv,       // [B, N]
    float* __restrict__ partials)       // [B*SPLITS, DIM]
{
    __shared__ unsigned int S_s[DIM];   // 32 KB fixed-point accumulators

    const int tid   = threadIdx.x;
    const int split = blockIdx.x;
    const int b     = blockIdx.y;

    uint4* ss4 = (uint4*)S_s;
    #pragma unroll
    for (int i = tid; i < DIM / 4; i += BLOCK) {
        ss4[i] = make_uint4(0u, 0u, 0u, 0u);
    }
    __syncthreads();

    const float2* xprow = x_pair + (size_t)b * DIM;
    const size_t base = (size_t)b * NPTS + (size_t)split * PTS_PER_BLOCK;
    const float2* idx2 = (const float2*)ri + base;
    const float*  val  = rv + base;

    #pragma unroll 4
    for (int i = tid; i < PTS_PER_BLOCK; i += BLOCK) {
        float2 r = idx2[i];
        float v  = val[i];

        float f0 = floorf(r.x), c0 = ceilf(r.x);
        float f1 = floorf(r.y), c1 = ceilf(r.y);
        // Per reference: w = 1 - |corner - real|, floor/ceil independently
        // (both corners get weight 1 when floor==ceil -> double count).
        float wf0 = 1.0f - (r.x - f0), wc0 = 1.0f - (c0 - r.x);
        float wf1 = 1.0f - (r.y - f1), wc1 = 1.0f - (c1 - r.y);

        // ONE scattered b64 VMEM gather: (x[f1], x[f1+1]).
        float2 g = xprow[(int)f1];
        float xa = g.x;
        float xb = (c1 == f1) ? xa : g.y;   // integral r.y: both corners x[f1]

        float vg = v * (wf1 * xa + wc1 * xb);
        // Fixed-point integer LDS atomics (ds_add_u32, per-bank full-rate;
        // wraparound-exact for signed via two's complement).
        int ia = __float2int_rn(wf0 * vg * FP_SCALE);
        int ib = __float2int_rn(wc0 * vg * FP_SCALE);
        atomicAdd(&S_s[(int)f0], (unsigned int)ia);
        atomicAdd(&S_s[(int)c0], (unsigned int)ib);
    }
    __syncthreads();

    // Decode fixed-point -> fp32, coalesced store of the partial row.
    float* out = partials + ((size_t)b * SPLITS + split) * DIM;
    for (int i = tid; i < DIM; i += BLOCK) {
        out[i] = (float)(int)S_s[i] * FP_INV;
    }
}

// y[b][d] = sum_s partials[b*SPLITS+s][d]; one float4 per thread.
__global__ __launch_bounds__(256) void reduce_partials_kernel(
    const float* __restrict__ partials, float* __restrict__ y)
{
    const int d4 = blockIdx.x * 256 + threadIdx.x;      // [0, B*DIM/4)
    const int b   = d4 / (DIM / 4);
    const int off = d4 % (DIM / 4);
    const float4* p = (const float4*)(partials + (size_t)b * SPLITS * DIM) + off;
    float4 acc = make_float4(0.f, 0.f, 0.f, 0.f);
    #pragma unroll
    for (int s = 0; s < SPLITS; ++s) {
        float4 v = p[(size_t)s * (DIM / 4)];
        acc.x += v.x; acc.y += v.y; acc.z += v.z; acc.w += v.w;
    }
    ((float4*)y)[d4] = acc;
}

// Fallback (ws too small): R10-style fp32 path + global-atomic flush.
__global__ __launch_bounds__(BLOCK, 4) void hyper_scatter_atomic_kernel(
    const float* __restrict__ x, const float* __restrict__ ri,
    const float* __restrict__ rv, float* __restrict__ y)
{
    __shared__ float y_s[DIM];
    const int tid = threadIdx.x, split = blockIdx.x, b = blockIdx.y;
    float4* ys4 = (float4*)y_s;
    for (int i = tid; i < DIM / 4; i += BLOCK) {
        ys4[i] = make_float4(0.f, 0.f, 0.f, 0.f);
    }
    __syncthreads();
    const float* xrow = x + (size_t)b * DIM;
    const size_t base = (size_t)b * NPTS + (size_t)split * PTS_PER_BLOCK;
    const float2* idx2 = (const float2*)ri + base;
    const float*  val  = rv + base;
    for (int i = tid; i < PTS_PER_BLOCK; i += BLOCK) {
        float2 r = idx2[i];
        float v  = val[i];
        float f0 = floorf(r.x), c0 = ceilf(r.x);
        float f1 = floorf(r.y), c1 = ceilf(r.y);
        float wf0 = 1.0f - (r.x - f0), wc0 = 1.0f - (c0 - r.x);
        float wf1 = 1.0f - (r.y - f1), wc1 = 1.0f - (c1 - r.y);
        float vg = v * (wf1 * xrow[(int)f1] + wc1 * xrow[(int)c1]);
        unsafeAtomicAdd(&y_s[(int)f0], wf0 * vg);
        unsafeAtomicAdd(&y_s[(int)c0], wc0 * vg);
    }
    __syncthreads();
    float* yrow = y + (size_t)b * DIM;
    for (int i = tid; i < DIM; i += BLOCK) atomicAdd(&yrow[i], y_s[i]);
}

extern "C" void kernel_launch(void* const* d_in, const int* in_sizes, int n_in,
                              void* d_out, int out_size, void* d_ws, size_t ws_size,
                              hipStream_t stream) {
    const float* x  = (const float*)d_in[0];
    const float* ri = (const float*)d_in[1];
    const float* rv = (const float*)d_in[2];
    float* y = (float*)d_out;

    const size_t part_bytes = (size_t)BATCH * SPLITS * DIM * sizeof(float); // 16 MB
    const size_t pair_bytes = (size_t)BATCH * DIM * sizeof(float2);         // 1 MB
    dim3 grid(SPLITS, BATCH);

    if (ws_size >= part_bytes + pair_bytes) {
        float* partials = (float*)d_ws;
        float2* x_pair  = (float2*)((char*)d_ws + part_bytes);
        make_pairs_kernel<<<BATCH * DIM / 256, 256, 0, stream>>>(x, x_pair);
        hyper_scatter_kernel<<<grid, BLOCK, 0, stream>>>(x_pair, ri, rv, partials);
        const int n4 = BATCH * DIM / 4;  // 32768
        reduce_partials_kernel<<<n4 / 256, 256, 0, stream>>>(partials, y);
    } else {
        hipMemsetAsync(y, 0, (size_t)out_size * sizeof(float), stream);
        hyper_scatter_atomic_kernel<<<grid, BLOCK, 0, stream>>>(x, ri, rv, y);
    }
}

// Round 14
// 99.156 us; speedup vs baseline: 1.3050x; 1.1515x over previous
//
#include <hip/hip_runtime.h>

// HyperLayer: y[b, f0/c0] += v * w0 * (wf1*x[b,f1] + wc1*x[b,c1])
// B=16, N=262144, DIM=8192.
// R14: R13 (fixed-point ds_add_u32 instead of ds_add_f32) cut scatter
// 50 -> ~36us, confirming the LDS FP-atomic serialization wall. Residual
// suspect: the scattered b64 VMEM gather (~25us of divergent L1 probes,
// previously hidden under the f32-atomic wall). Move the gather back to
// LDS (scattered ds_read measured near-free: 660K conflict cyc grid-wide).
// Keep int32 fixed-point accumulator. make_pairs kernel deleted.

#define BATCH 16
#define NPTS 262144
#define DIM 8192
#define SPLITS 32
#define PTS_PER_BLOCK (NPTS / SPLITS)   // 8192
#define BLOCK 512

#define FP_SCALE 4194304.0f             // 2^22
#define FP_INV   (1.0f / 4194304.0f)

__global__ __launch_bounds__(BLOCK, 4) void hyper_scatter_kernel(
    const float* __restrict__ x,    // [B, DIM]
    const float* __restrict__ ri,   // [B, N, 2]
    const float* __restrict__ rv,   // [B, N]
    float* __restrict__ partials)   // [B*SPLITS, DIM]
{
    __shared__ float        x_s[DIM];   // 32 KB staged x row (LDS gather)
    __shared__ unsigned int S_s[DIM];   // 32 KB fixed-point accumulators

    const int tid   = threadIdx.x;
    const int split = blockIdx.x;
    const int b     = blockIdx.y;

    const float4* x4 = (const float4*)(x + (size_t)b * DIM);
    float4* xs4 = (float4*)x_s;
    uint4*  ss4 = (uint4*)S_s;
    #pragma unroll
    for (int i = tid; i < DIM / 4; i += BLOCK) {
        xs4[i] = x4[i];
        ss4[i] = make_uint4(0u, 0u, 0u, 0u);
    }
    __syncthreads();

    const size_t base = (size_t)b * NPTS + (size_t)split * PTS_PER_BLOCK;
    const float2* idx2 = (const float2*)ri + base;
    const float*  val  = rv + base;

    #pragma unroll 4
    for (int i = tid; i < PTS_PER_BLOCK; i += BLOCK) {
        float2 r = idx2[i];
        float v  = val[i];

        float f0 = floorf(r.x), c0 = ceilf(r.x);
        float f1 = floorf(r.y), c1 = ceilf(r.y);
        // Per reference: w = 1 - |corner - real|, floor/ceil independently
        // (both corners get weight 1 when floor==ceil -> double count).
        float wf0 = 1.0f - (r.x - f0), wc0 = 1.0f - (c0 - r.x);
        float wf1 = 1.0f - (r.y - f1), wc1 = 1.0f - (c1 - r.y);

        // Scattered LDS gather (near-free; conflicts ~2.6K cyc/CU total).
        float xa = x_s[(int)f1];
        float xb = x_s[(int)c1];

        float vg = v * (wf1 * xa + wc1 * xb);
        // Fixed-point integer LDS atomics (per-bank full-rate; wraparound-
        // exact two's complement; |per-slot-per-block sum| << 2^31).
        int ia = __float2int_rn(wf0 * vg * FP_SCALE);
        int ib = __float2int_rn(wc0 * vg * FP_SCALE);
        atomicAdd(&S_s[(int)f0], (unsigned int)ia);
        atomicAdd(&S_s[(int)c0], (unsigned int)ib);
    }
    __syncthreads();

    // Decode fixed-point -> fp32, coalesced store of the partial row.
    float* out = partials + ((size_t)b * SPLITS + split) * DIM;
    for (int i = tid; i < DIM; i += BLOCK) {
        out[i] = (float)(int)S_s[i] * FP_INV;
    }
}

// y[b][d] = sum_s partials[b*SPLITS+s][d]; one float4 per thread.
__global__ __launch_bounds__(256) void reduce_partials_kernel(
    const float* __restrict__ partials, float* __restrict__ y)
{
    const int d4 = blockIdx.x * 256 + threadIdx.x;      // [0, B*DIM/4)
    const int b   = d4 / (DIM / 4);
    const int off = d4 % (DIM / 4);
    const float4* p = (const float4*)(partials + (size_t)b * SPLITS * DIM) + off;
    float4 acc = make_float4(0.f, 0.f, 0.f, 0.f);
    #pragma unroll
    for (int s = 0; s < SPLITS; ++s) {
        float4 v = p[(size_t)s * (DIM / 4)];
        acc.x += v.x; acc.y += v.y; acc.z += v.z; acc.w += v.w;
    }
    ((float4*)y)[d4] = acc;
}

// Fallback (ws too small): fp32 LDS accumulate + global-atomic flush.
__global__ __launch_bounds__(BLOCK, 4) void hyper_scatter_atomic_kernel(
    const float* __restrict__ x, const float* __restrict__ ri,
    const float* __restrict__ rv, float* __restrict__ y)
{
    __shared__ float x_s[DIM];
    __shared__ float y_s[DIM];
    const int tid = threadIdx.x, split = blockIdx.x, b = blockIdx.y;
    const float4* x4 = (const float4*)(x + (size_t)b * DIM);
    float4* xs4 = (float4*)x_s;
    float4* ys4 = (float4*)y_s;
    for (int i = tid; i < DIM / 4; i += BLOCK) {
        xs4[i] = x4[i];
        ys4[i] = make_float4(0.f, 0.f, 0.f, 0.f);
    }
    __syncthreads();
    const size_t base = (size_t)b * NPTS + (size_t)split * PTS_PER_BLOCK;
    const float2* idx2 = (const float2*)ri + base;
    const float*  val  = rv + base;
    for (int i = tid; i < PTS_PER_BLOCK; i += BLOCK) {
        float2 r = idx2[i];
        float v  = val[i];
        float f0 = floorf(r.x), c0 = ceilf(r.x);
        float f1 = floorf(r.y), c1 = ceilf(r.y);
        float wf0 = 1.0f - (r.x - f0), wc0 = 1.0f - (c0 - r.x);
        float wf1 = 1.0f - (r.y - f1), wc1 = 1.0f - (c1 - r.y);
        float vg = v * (wf1 * x_s[(int)f1] + wc1 * x_s[(int)c1]);
        unsafeAtomicAdd(&y_s[(int)f0], wf0 * vg);
        unsafeAtomicAdd(&y_s[(int)c0], wc0 * vg);
    }
    __syncthreads();
    float* yrow = y + (size_t)b * DIM;
    for (int i = tid; i < DIM; i += BLOCK) atomicAdd(&yrow[i], y_s[i]);
}

extern "C" void kernel_launch(void* const* d_in, const int* in_sizes, int n_in,
                              void* d_out, int out_size, void* d_ws, size_t ws_size,
                              hipStream_t stream) {
    const float* x  = (const float*)d_in[0];
    const float* ri = (const float*)d_in[1];
    const float* rv = (const float*)d_in[2];
    float* y = (float*)d_out;

    const size_t part_bytes = (size_t)BATCH * SPLITS * DIM * sizeof(float); // 16 MB
    dim3 grid(SPLITS, BATCH);

    if (ws_size >= part_bytes) {
        float* partials = (float*)d_ws;
        hyper_scatter_kernel<<<grid, BLOCK, 0, stream>>>(x, ri, rv, partials);
        const int n4 = BATCH * DIM / 4;  // 32768
        reduce_partials_kernel<<<n4 / 256, 256, 0, stream>>>(partials, y);
    } else {
        hipMemsetAsync(y, 0, (size_t)out_size * sizeof(float), stream);
        hyper_scatter_atomic_kernel<<<grid, BLOCK, 0, stream>>>(x, ri, rv, y);
    }
}

// Round 15
// 98.756 us; speedup vs baseline: 1.3102x; 1.0041x over previous
//
#include <hip/hip_runtime.h>

// HyperLayer: y[b, f0/c0] += v * w0 * (wf1*x[b,f1] + wc1*x[b,c1])
// B=16, N=262144, DIM=8192.
// R15: R14 (LDS gather + fixed-point ds_add_u32 + partials) = 99.2us total,
// of which ~78us is harness ws-poison overhead; controllable ~21us.
// This round: SPLITS 32->16 (partials 16->8MB), BLOCK 512->1024 (keeps
// 16 waves/CU at 256 blocks), frac-based weights (fewer VALU ops; exactly
// preserves integral-index double-count: frac==0 -> w=1+1 on same slot).

#define BATCH 16
#define NPTS 262144
#define DIM 8192
#define SPLITS 16
#define PTS_PER_BLOCK (NPTS / SPLITS)   // 16384
#define BLOCK 1024

#define FP_SCALE 4194304.0f             // 2^22
#define FP_INV   (1.0f / 4194304.0f)

__global__ __launch_bounds__(BLOCK, 8) void hyper_scatter_kernel(
    const float* __restrict__ x,    // [B, DIM]
    const float* __restrict__ ri,   // [B, N, 2]
    const float* __restrict__ rv,   // [B, N]
    float* __restrict__ partials)   // [B*SPLITS, DIM]
{
    __shared__ float        x_s[DIM];   // 32 KB staged x row (LDS gather)
    __shared__ unsigned int S_s[DIM];   // 32 KB fixed-point accumulators

    const int tid   = threadIdx.x;
    const int split = blockIdx.x;
    const int b     = blockIdx.y;

    const float4* x4 = (const float4*)(x + (size_t)b * DIM);
    float4* xs4 = (float4*)x_s;
    uint4*  ss4 = (uint4*)S_s;
    #pragma unroll
    for (int i = tid; i < DIM / 4; i += BLOCK) {
        xs4[i] = x4[i];
        ss4[i] = make_uint4(0u, 0u, 0u, 0u);
    }
    __syncthreads();

    const size_t base = (size_t)b * NPTS + (size_t)split * PTS_PER_BLOCK;
    const float2* idx2 = (const float2*)ri + base;
    const float*  val  = rv + base;

    #pragma unroll 4
    for (int i = tid; i < PTS_PER_BLOCK; i += BLOCK) {
        float2 r = idx2[i];
        float v  = val[i];

        // frac-based corner weights. Reference semantics: w = 1-|corner-real|
        // for floor and ceil independently; integral index -> floor==ceil,
        // both weights 1, both land on the same slot (double count).
        float f0 = floorf(r.x);
        float fr0 = r.x - f0;                 // in [0,1)
        float wf0 = 1.0f - fr0;
        bool  int0 = (fr0 == 0.0f);
        float wc0 = int0 ? 1.0f : fr0;
        int   i0f = (int)f0;
        int   i0c = i0f + (int0 ? 0 : 1);

        float f1 = floorf(r.y);
        float fr1 = r.y - f1;
        float wf1 = 1.0f - fr1;
        bool  int1 = (fr1 == 0.0f);
        float wc1 = int1 ? 1.0f : fr1;
        int   i1f = (int)f1;
        int   i1c = i1f + (int1 ? 0 : 1);

        // Scattered LDS gather (near-free).
        float xa = x_s[i1f];
        float xb = x_s[i1c];

        float vg = v * (wf1 * xa + wc1 * xb);
        // Fixed-point integer LDS atomics (per-bank full-rate; wraparound-
        // exact two's complement).
        int ia = __float2int_rn(wf0 * vg * FP_SCALE);
        int ib = __float2int_rn(wc0 * vg * FP_SCALE);
        atomicAdd(&S_s[i0f], (unsigned int)ia);
        atomicAdd(&S_s[i0c], (unsigned int)ib);
    }
    __syncthreads();

    // Decode fixed-point -> fp32, coalesced store of the partial row.
    float* out = partials + ((size_t)b * SPLITS + split) * DIM;
    for (int i = tid; i < DIM; i += BLOCK) {
        out[i] = (float)(int)S_s[i] * FP_INV;
    }
}

// y[b][d] = sum_s partials[b*SPLITS+s][d]; one float4 per thread.
__global__ __launch_bounds__(256) void reduce_partials_kernel(
    const float* __restrict__ partials, float* __restrict__ y)
{
    const int d4 = blockIdx.x * 256 + threadIdx.x;      // [0, B*DIM/4)
    const int b   = d4 / (DIM / 4);
    const int off = d4 % (DIM / 4);
    const float4* p = (const float4*)(partials + (size_t)b * SPLITS * DIM) + off;
    float4 acc = make_float4(0.f, 0.f, 0.f, 0.f);
    #pragma unroll
    for (int s = 0; s < SPLITS; ++s) {
        float4 v = p[(size_t)s * (DIM / 4)];
        acc.x += v.x; acc.y += v.y; acc.z += v.z; acc.w += v.w;
    }
    ((float4*)y)[d4] = acc;
}

// Fallback (ws too small): fp32 LDS accumulate + global-atomic flush.
__global__ __launch_bounds__(BLOCK, 8) void hyper_scatter_atomic_kernel(
    const float* __restrict__ x, const float* __restrict__ ri,
    const float* __restrict__ rv, float* __restrict__ y)
{
    __shared__ float x_s[DIM];
    __shared__ float y_s[DIM];
    const int tid = threadIdx.x, split = blockIdx.x, b = blockIdx.y;
    const float4* x4 = (const float4*)(x + (size_t)b * DIM);
    float4* xs4 = (float4*)x_s;
    float4* ys4 = (float4*)y_s;
    for (int i = tid; i < DIM / 4; i += BLOCK) {
        xs4[i] = x4[i];
        ys4[i] = make_float4(0.f, 0.f, 0.f, 0.f);
    }
    __syncthreads();
    const size_t base = (size_t)b * NPTS + (size_t)split * PTS_PER_BLOCK;
    const float2* idx2 = (const float2*)ri + base;
    const float*  val  = rv + base;
    for (int i = tid; i < PTS_PER_BLOCK; i += BLOCK) {
        float2 r = idx2[i];
        float v  = val[i];
        float f0 = floorf(r.x), c0 = ceilf(r.x);
        float f1 = floorf(r.y), c1 = ceilf(r.y);
        float wf0 = 1.0f - (r.x - f0), wc0 = 1.0f - (c0 - r.x);
        float wf1 = 1.0f - (r.y - f1), wc1 = 1.0f - (c1 - r.y);
        float vg = v * (wf1 * x_s[(int)f1] + wc1 * x_s[(int)c1]);
        unsafeAtomicAdd(&y_s[(int)f0], wf0 * vg);
        unsafeAtomicAdd(&y_s[(int)c0], wc0 * vg);
    }
    __syncthreads();
    float* yrow = y + (size_t)b * DIM;
    for (int i = tid; i < DIM; i += BLOCK) atomicAdd(&yrow[i], y_s[i]);
}

extern "C" void kernel_launch(void* const* d_in, const int* in_sizes, int n_in,
                              void* d_out, int out_size, void* d_ws, size_t ws_size,
                              hipStream_t stream) {
    const float* x  = (const float*)d_in[0];
    const float* ri = (const float*)d_in[1];
    const float* rv = (const float*)d_in[2];
    float* y = (float*)d_out;

    const size_t part_bytes = (size_t)BATCH * SPLITS * DIM * sizeof(float); // 8 MB
    dim3 grid(SPLITS, BATCH);

    if (ws_size >= part_bytes) {
        float* partials = (float*)d_ws;
        hyper_scatter_kernel<<<grid, BLOCK, 0, stream>>>(x, ri, rv, partials);
        const int n4 = BATCH * DIM / 4;  // 32768
        reduce_partials_kernel<<<n4 / 256, 256, 0, stream>>>(partials, y);
    } else {
        hipMemsetAsync(y, 0, (size_t)out_size * sizeof(float), stream);
        hyper_scatter_atomic_kernel<<<grid, BLOCK, 0, stream>>>(x, ri, rv, y);
    }
}